// Round 3
// baseline (10356.499 us; speedup 1.0000x reference)
//
#include <hip/hip_runtime.h>
#include <math.h>

namespace {
constexpr int L_ = 4, H_ = 4, D_ = 128, DFF_ = 512, T_ = 64, B_ = 1024;
constexpr int S_ = 4, BOS_ = 4, DH_ = 32;
constexpr int NB = 4;                 // batch elements per block
constexpr int NBLK = B_ / NB;         // 256 blocks
constexpr int NTH = 512;              // threads per block

// workspace: KV cache only (exactly 256 MiB)
constexpr size_t KC_BLK = (size_t)L_ * NB * T_ * D_;        // floats per block
constexpr size_t KC_OFF = 0;
constexpr size_t VC_OFF = KC_OFF + (size_t)NBLK * KC_BLK;
}

__device__ __forceinline__ float4 ld4(const float* p) {
  return *reinterpret_cast<const float4*>(p);
}

__device__ __forceinline__ float gelu_exact(float v) {
  return 0.5f * v * (1.0f + erff(v * 0.70710678118654752440f));
}

// one wave normalizes one 128-vector: lane holds src[lane], src[lane+64]
__device__ __forceinline__ void ln_wave(const float* __restrict__ src,
                                        float* __restrict__ dst,
                                        const float* __restrict__ w,
                                        const float* __restrict__ b, int lane) {
  float v0 = src[lane], v1 = src[lane + 64];
  float s = v0 + v1;
#pragma unroll
  for (int off = 32; off > 0; off >>= 1) s += __shfl_xor(s, off);
  float mu = s * (1.f / 128.f);
  float d0 = v0 - mu, d1 = v1 - mu;
  float s2 = d0 * d0 + d1 * d1;
#pragma unroll
  for (int off = 32; off > 0; off >>= 1) s2 += __shfl_xor(s2, off);
  float inv = 1.f / sqrtf(s2 * (1.f / 128.f) + 1e-5f);
  dst[lane] = d0 * inv * w[lane] + b[lane];
  dst[lane + 64] = d1 * inv * w[lane + 64] + b[lane + 64];
}

__global__ __launch_bounds__(NTH, 2) void decode_kernel(
    const float* __restrict__ gumbel, const float* __restrict__ state_emb,
    const float* __restrict__ pos_emb,
    const float* __restrict__ ln1w, const float* __restrict__ ln1b,
    const float* __restrict__ wqkv, const float* __restrict__ bqkv,
    const float* __restrict__ wo, const float* __restrict__ bo,
    const float* __restrict__ ln2w, const float* __restrict__ ln2b,
    const float* __restrict__ w1, const float* __restrict__ b1,
    const float* __restrict__ w2, const float* __restrict__ b2,
    const float* __restrict__ fnw, const float* __restrict__ fnb,
    const float* __restrict__ headw, const float* __restrict__ headb,
    const int* __restrict__ nalpha, const int* __restrict__ nbeta,
    float* __restrict__ ws, float* __restrict__ out) {
  const int tid = threadIdx.x;
  const int blk = blockIdx.x;
  const int lane = tid & 63;
  const int wv = tid >> 6;
  const int slot = tid >> 2;   // 0..127
  const int dq = tid & 3;      // 0..3

  float* Kc = ws + KC_OFF + (size_t)blk * KC_BLK;
  float* Vc = ws + VC_OFF + (size_t)blk * KC_BLK;

  __shared__ __align__(16) float xres[NB][D_];
  __shared__ __align__(16) float xn[NB][D_];
  __shared__ __align__(16) float qbuf[NB][D_];     // q, later ctx
  __shared__ __align__(16) float hbuf[NB][DFF_];
  __shared__ __align__(16) float sc[NB][H_][T_];   // final softmax probs
  __shared__ float logits[NB][S_];
  __shared__ int tok[NB], arem[NB], brem[NB];
  __shared__ float lpsum[NB];

  if (tid < NB) {
    tok[tid] = BOS_;
    arem[tid] = nalpha[0];
    brem[tid] = nbeta[0];
    lpsum[tid] = 0.f;
  }
  __syncthreads();

  // ctx-phase mapping (constant per thread)
  const int ce = slot >> 5;        // element
  const int cc = slot & 31;        // float4 chunk within row (d = 4*cc..4*cc+3)
  const int ch = cc >> 3;          // head

  for (int i = 0; i < T_; ++i) {
    // ---- embed
    {
      const int e = tid >> 7, d = tid & 127;
      xres[e][d] = state_emb[tok[e] * D_ + d] + pos_emb[i * D_ + d];
    }
    __syncthreads();

    for (int l = 0; l < L_; ++l) {
      // ---- LN1 (1 barrier)
      if (wv < NB) ln_wave(xres[wv], xn[wv], ln1w + l * D_, ln1b + l * D_, lane);
      __syncthreads();

      // ---- fused QKV GEMV: rows (slot, slot+128, slot+256); x read once
      {
        float acc[3][4];
#pragma unroll
        for (int p = 0; p < 3; ++p)
#pragma unroll
          for (int e = 0; e < 4; ++e) acc[p][e] = 0.f;
        const float* wbase = wqkv + ((size_t)l * 384 + slot) * D_;
#pragma unroll
        for (int j = 0; j < 8; ++j) {
          const int d0 = 16 * j + 4 * dq;
          float4 xv[4];
#pragma unroll
          for (int e = 0; e < 4; ++e) xv[e] = ld4(&xn[e][d0]);
#pragma unroll
          for (int p = 0; p < 3; ++p) {
            const float4 w4 = ld4(wbase + (size_t)(p * 128) * D_ + d0);
#pragma unroll
            for (int e = 0; e < 4; ++e) {
              acc[p][e] += w4.x * xv[e].x + w4.y * xv[e].y +
                           w4.z * xv[e].z + w4.w * xv[e].w;
            }
          }
        }
#pragma unroll
        for (int p = 0; p < 3; ++p) {
#pragma unroll
          for (int e = 0; e < 4; ++e) {
            acc[p][e] += __shfl_xor(acc[p][e], 1);
            acc[p][e] += __shfl_xor(acc[p][e], 2);
          }
          float r = (dq == 0) ? acc[p][0] : (dq == 1) ? acc[p][1]
                   : (dq == 2) ? acc[p][2] : acc[p][3];
          r += bqkv[l * 384 + p * 128 + slot];
          if (p == 0) {
            qbuf[dq][slot] = r;
          } else if (p == 1) {
            Kc[(((size_t)l * NB + dq) * T_ + i) * D_ + slot] = r;
          } else {
            Vc[(((size_t)l * NB + dq) * T_ + i) * D_ + slot] = r;
          }
        }
      }
      __syncthreads();

      // ---- V prefetch (issue-early) + scores + softmax (in-register)
      float4 vreg[16];
      {
        const float* vpb = Vc + ((size_t)l * NB + ce) * T_ * D_ + cc * 4;
#pragma unroll
        for (int jj = 0; jj < 16; ++jj) {
          const int t = 4 * jj + dq;
          if (t <= i) vreg[jj] = ld4(vpb + (size_t)t * D_);
        }
        // scores: pid = (e,h), lane j covers t = j, j+32
        const int pid = tid >> 5, j = tid & 31;
        const int e = pid >> 2, h = pid & 3;
        const float4* q4 = reinterpret_cast<const float4*>(&qbuf[e][h * DH_]);
        const float* kb = Kc + ((size_t)l * NB + e) * T_ * D_ + h * DH_;
        float s0 = -INFINITY, s1 = -INFINITY;
        if (j <= i) {
          const float4* kp = reinterpret_cast<const float4*>(kb + (size_t)j * D_);
          float a = 0.f;
#pragma unroll
          for (int k = 0; k < 8; ++k) {
            float4 qv = q4[k], kv = kp[k];
            a += qv.x * kv.x + qv.y * kv.y + qv.z * kv.z + qv.w * kv.w;
          }
          s0 = a * 0.17677669529663687f;
        }
        if (j + 32 <= i) {
          const float4* kp = reinterpret_cast<const float4*>(kb + (size_t)(j + 32) * D_);
          float a = 0.f;
#pragma unroll
          for (int k = 0; k < 8; ++k) {
            float4 qv = q4[k], kv = kp[k];
            a += qv.x * kv.x + qv.y * kv.y + qv.z * kv.z + qv.w * kv.w;
          }
          s1 = a * 0.17677669529663687f;
        }
        float m = fmaxf(s0, s1);
#pragma unroll
        for (int off = 16; off > 0; off >>= 1) m = fmaxf(m, __shfl_xor(m, off, 32));
        float p0 = expf(s0 - m), p1 = expf(s1 - m);
        float sum = p0 + p1;
#pragma unroll
        for (int off = 16; off > 0; off >>= 1) sum += __shfl_xor(sum, off, 32);
        float inv = 1.f / sum;
        sc[e][h][j] = p0 * inv;
        sc[e][h][j + 32] = p1 * inv;
      }
      __syncthreads();

      // ---- ctx = P·V from prefetched registers; write to qbuf
      {
        float ax = 0.f, ay = 0.f, az = 0.f, aw = 0.f;
#pragma unroll
        for (int jj = 0; jj < 16; ++jj) {
          const int t = 4 * jj + dq;
          if (t <= i) {
            const float p = sc[ce][ch][t];
            ax += p * vreg[jj].x;
            ay += p * vreg[jj].y;
            az += p * vreg[jj].z;
            aw += p * vreg[jj].w;
          }
        }
        ax += __shfl_xor(ax, 1); ax += __shfl_xor(ax, 2);
        ay += __shfl_xor(ay, 1); ay += __shfl_xor(ay, 2);
        az += __shfl_xor(az, 1); az += __shfl_xor(az, 2);
        aw += __shfl_xor(aw, 1); aw += __shfl_xor(aw, 2);
        if (dq == 0) {
          float4 r = {ax, ay, az, aw};
          *reinterpret_cast<float4*>(&qbuf[ce][cc * 4]) = r;
        }
      }
      __syncthreads();

      // ---- x += ctx @ wo.T + bo
      {
        const float* wrow = wo + ((size_t)l * 128 + slot) * D_;
        float a0 = 0.f, a1 = 0.f, a2 = 0.f, a3 = 0.f;
#pragma unroll
        for (int j = 0; j < 8; ++j) {
          const int d0 = 16 * j + 4 * dq;
          const float4 w4 = ld4(wrow + d0);
          const float4 x0 = ld4(&qbuf[0][d0]);
          const float4 x1 = ld4(&qbuf[1][d0]);
          const float4 x2 = ld4(&qbuf[2][d0]);
          const float4 x3 = ld4(&qbuf[3][d0]);
          a0 += w4.x * x0.x + w4.y * x0.y + w4.z * x0.z + w4.w * x0.w;
          a1 += w4.x * x1.x + w4.y * x1.y + w4.z * x1.z + w4.w * x1.w;
          a2 += w4.x * x2.x + w4.y * x2.y + w4.z * x2.z + w4.w * x2.w;
          a3 += w4.x * x3.x + w4.y * x3.y + w4.z * x3.z + w4.w * x3.w;
        }
        a0 += __shfl_xor(a0, 1); a0 += __shfl_xor(a0, 2);
        a1 += __shfl_xor(a1, 1); a1 += __shfl_xor(a1, 2);
        a2 += __shfl_xor(a2, 1); a2 += __shfl_xor(a2, 2);
        a3 += __shfl_xor(a3, 1); a3 += __shfl_xor(a3, 2);
        float r = (dq == 0) ? a0 : (dq == 1) ? a1 : (dq == 2) ? a2 : a3;
        xres[dq][slot] += r + bo[l * D_ + slot];
      }
      __syncthreads();

      // ---- LN2 (1 barrier)
      if (wv < NB) ln_wave(xres[wv], xn[wv], ln2w + l * D_, ln2b + l * D_, lane);
      __syncthreads();

      // ---- fused FFN1 + GELU: rows slot+{0,128,256,384}; x read once
      {
        float acc[4][4];
#pragma unroll
        for (int p = 0; p < 4; ++p)
#pragma unroll
          for (int e = 0; e < 4; ++e) acc[p][e] = 0.f;
        const float* wbase = w1 + ((size_t)l * DFF_ + slot) * D_;
#pragma unroll
        for (int j = 0; j < 8; ++j) {
          const int d0 = 16 * j + 4 * dq;
          float4 xv[4];
#pragma unroll
          for (int e = 0; e < 4; ++e) xv[e] = ld4(&xn[e][d0]);
#pragma unroll
          for (int p = 0; p < 4; ++p) {
            const float4 w4 = ld4(wbase + (size_t)(p * 128) * D_ + d0);
#pragma unroll
            for (int e = 0; e < 4; ++e) {
              acc[p][e] += w4.x * xv[e].x + w4.y * xv[e].y +
                           w4.z * xv[e].z + w4.w * xv[e].w;
            }
          }
        }
#pragma unroll
        for (int p = 0; p < 4; ++p) {
#pragma unroll
          for (int e = 0; e < 4; ++e) {
            acc[p][e] += __shfl_xor(acc[p][e], 1);
            acc[p][e] += __shfl_xor(acc[p][e], 2);
          }
          float r = (dq == 0) ? acc[p][0] : (dq == 1) ? acc[p][1]
                   : (dq == 2) ? acc[p][2] : acc[p][3];
          hbuf[dq][p * 128 + slot] = gelu_exact(r + b1[l * DFF_ + p * 128 + slot]);
        }
      }
      __syncthreads();

      // ---- FFN2: x += hbuf @ w2.T + b2
      {
        const float* wrow = w2 + ((size_t)l * 128 + slot) * DFF_;
        float a0 = 0.f, a1 = 0.f, a2 = 0.f, a3 = 0.f;
#pragma unroll
        for (int j = 0; j < 32; ++j) {
          const int d0 = 16 * j + 4 * dq;
          const float4 w4 = ld4(wrow + d0);
          const float4 x0 = ld4(&hbuf[0][d0]);
          const float4 x1 = ld4(&hbuf[1][d0]);
          const float4 x2 = ld4(&hbuf[2][d0]);
          const float4 x3 = ld4(&hbuf[3][d0]);
          a0 += w4.x * x0.x + w4.y * x0.y + w4.z * x0.z + w4.w * x0.w;
          a1 += w4.x * x1.x + w4.y * x1.y + w4.z * x1.z + w4.w * x1.w;
          a2 += w4.x * x2.x + w4.y * x2.y + w4.z * x2.z + w4.w * x2.w;
          a3 += w4.x * x3.x + w4.y * x3.y + w4.z * x3.z + w4.w * x3.w;
        }
        a0 += __shfl_xor(a0, 1); a0 += __shfl_xor(a0, 2);
        a1 += __shfl_xor(a1, 1); a1 += __shfl_xor(a1, 2);
        a2 += __shfl_xor(a2, 1); a2 += __shfl_xor(a2, 2);
        a3 += __shfl_xor(a3, 1); a3 += __shfl_xor(a3, 2);
        float r = (dq == 0) ? a0 : (dq == 1) ? a1 : (dq == 2) ? a2 : a3;
        xres[dq][slot] += r + b2[l * D_ + slot];
      }
      __syncthreads();
    }  // layers

    // ---- final LN (1 barrier)
    if (wv < NB) ln_wave(xres[wv], xn[wv], fnw, fnb, lane);
    __syncthreads();

    // ---- head
    if (tid < 128) {
      const int e = tid >> 5, rest = tid & 31, s = rest >> 3, j = rest & 7;
      const float4* xv = reinterpret_cast<const float4*>(xn[e]);
      const float4* hw = reinterpret_cast<const float4*>(headw + s * D_);
      float acc = 0.f;
#pragma unroll
      for (int k = 4 * j; k < 4 * j + 4; ++k) {
        float4 a = xv[k], w = hw[k];
        acc += a.x * w.x + a.y * w.y + a.z * w.z + a.w * w.w;
      }
      acc += __shfl_xor(acc, 1);
      acc += __shfl_xor(acc, 2);
      acc += __shfl_xor(acc, 4);
      if (j == 0) logits[e][s] = acc + headb[s];
    }
    __syncthreads();

    // ---- mask + log-softmax + gumbel-argmax
    if (tid < NB) {
      const int e = tid;
      const int b = blk * NB + e;
      int a = arem[e], bb = brem[e];
      int oa = T_ - 1 - i;
      bool m[4];
      m[0] = (a <= oa) && (bb <= oa);
      m[1] = (bb > 0) && (a <= oa) && (bb - 1 <= oa);
      m[2] = (a > 0) && (a - 1 <= oa) && (bb <= oa);
      m[3] = (a > 0) && (bb > 0) && (a - 1 <= oa) && (bb - 1 <= oa);
      float mx = -INFINITY;
#pragma unroll
      for (int s = 0; s < 4; ++s)
        if (m[s]) mx = fmaxf(mx, logits[e][s]);
      float sum = 0.f;
      float lg[4];
#pragma unroll
      for (int s = 0; s < 4; ++s) {
        if (m[s]) {
          float z = logits[e][s] - mx;
          sum += expf(z);
          lg[s] = z;
        } else {
          lg[s] = -INFINITY;
        }
      }
      float lse = logf(sum);
      float best = -INFINITY;
      int bs = 0;
#pragma unroll
      for (int s = 0; s < 4; ++s) {
        float lp = lg[s] - lse;
        float y = lp + gumbel[(size_t)b * T_ * S_ + (size_t)i * S_ + s];
        if (y > best) { best = y; bs = s; }
      }
      lpsum[e] += lg[bs] - lse;
      out[(size_t)b * T_ + i] = (float)bs;
      tok[e] = bs;
      arem[e] = a - (bs >> 1);
      brem[e] = bb - (bs & 1);
    }
    __syncthreads();
  }  // steps

  if (tid < NB) out[(size_t)B_ * T_ + (size_t)blk * NB + tid] = lpsum[tid];
}

extern "C" void kernel_launch(void* const* d_in, const int* in_sizes, int n_in,
                              void* d_out, int out_size, void* d_ws, size_t ws_size,
                              hipStream_t stream) {
  const float* gumbel    = (const float*)d_in[0];
  const float* state_emb = (const float*)d_in[1];
  const float* pos_emb   = (const float*)d_in[2];
  const float* ln1w      = (const float*)d_in[3];
  const float* ln1b      = (const float*)d_in[4];
  const float* wqkv      = (const float*)d_in[5];
  const float* bqkv      = (const float*)d_in[6];
  const float* wo        = (const float*)d_in[7];
  const float* bo        = (const float*)d_in[8];
  const float* ln2w      = (const float*)d_in[9];
  const float* ln2b      = (const float*)d_in[10];
  const float* w1        = (const float*)d_in[11];
  const float* b1        = (const float*)d_in[12];
  const float* w2        = (const float*)d_in[13];
  const float* b2        = (const float*)d_in[14];
  const float* fnw       = (const float*)d_in[15];
  const float* fnb       = (const float*)d_in[16];
  const float* headw     = (const float*)d_in[17];
  const float* headb     = (const float*)d_in[18];
  const int* nalpha      = (const int*)d_in[19];
  const int* nbeta       = (const int*)d_in[20];
  float* ws = (float*)d_ws;
  float* out = (float*)d_out;

  decode_kernel<<<dim3(NBLK), dim3(NTH), 0, stream>>>(
      gumbel, state_emb, pos_emb, ln1w, ln1b, wqkv, bqkv, wo, bo, ln2w, ln2b,
      w1, b1, w2, b2, fnw, fnb, headw, headb, nalpha, nbeta, ws, out);
}